// Round 6
// baseline (222.660 us; speedup 1.0000x reference)
//
#include <hip/hip_runtime.h>
#include <hip/hip_cooperative_groups.h>
#include <math.h>

namespace cg = cooperative_groups;

#define B_   8
#define T_   12
#define BT   96      // B*T
#define N_   1000
#define FIN  64
#define H_   8
#define FOUT 16
#define HF   128     // H*FOUT
#define E_   8000

typedef unsigned short u16;
typedef unsigned int   u32;
typedef __attribute__((ext_vector_type(8))) short  short8;   // 8 bf16 (4 VGPR)
typedef __attribute__((ext_vector_type(4))) float  float4v;  // MFMA acc

__device__ __forceinline__ float bf2f(u16 u) {
    return __uint_as_float(((u32)u) << 16);
}
__device__ __forceinline__ void unpack2(u32 q, float& lo, float& hi) {
    lo = __uint_as_float(q << 16);
    hi = __uint_as_float(q & 0xffff0000u);
}
__device__ __forceinline__ u16 f2bf(float f) {
    u32 x = __float_as_uint(f);
    u32 r = (x + 0x7fffu + ((x >> 16) & 1u)) >> 16;   // RNE
    return (u16)r;
}
__device__ __forceinline__ u32 pack2bf(float lo, float hi) {
    return (u32)f2bf(lo) | ((u32)f2bf(hi) << 16);
}

// Fragment-permuted W' layout (see R2): conflict-free ds_read_b128 fragments.
__device__ __forceinline__ int wpos(int r, int c) {
    return (((r >> 4) * 8 + (c >> 5) * 4 + ((c >> 3) & 3)) * 16 + (r & 15)) * 8
           + (c & 7);
}

// ---------------------------------------------------------------------------
// Workspace carve (float-element offsets).
// ---------------------------------------------------------------------------
#define OFF_FLAGS   0         // 4 ints (unused now, kept for carve stability)
#define OFF_OFFS    264       // 1004 ints
#define OFF_CSR     1268      // 8000 ints (stores src*BT, grouped by target)
#define OFF_ST      17972     // 1536000 sT fp32 [n][bt][16]
#define OFF_PROJ    1553972   // projT bf16 [n][bt][128] = 12.288M u16
#define OFF_SKIP    7697972   // skipT bf16 [n][bt][128]

// ---------------------------------------------------------------------------
// FUSED kernel (cooperative, grid <= min(751, blocksPerCU*256), 512 thr):
//  Phase A: block 0 = probes + CSR build (wave-scan); blocks 1..G-1 = MFMA
//           GEMM chunks (128 rows each, W' built in LDS per block).
//  grid.sync()  (device-scope fence: projT/sT/csrS visible across XCDs)
//  Phase B: attention gather. Physical block p (XCD p&7) processes the same
//           XCD-pinned virtual units b = (p&7)*1500 + j as R4's remap, two
//           units per 512-thr block iteration (half = tid>>8). Per-wave csr
//           tile in LDS with explicit lgkmcnt(0) -> NO block barriers in the
//           divergent att loop (halves have different trip counts).
// ---------------------------------------------------------------------------
__global__ __launch_bounds__(512) void k_fused(const void* __restrict__ xin,
                                               const void* __restrict__ Wp,
                                               const void* __restrict__ Ws,
                                               const void* __restrict__ as_,
                                               const void* __restrict__ at_,
                                               const u32* __restrict__ ew,
                                               u16* __restrict__ projT,
                                               u16* __restrict__ skipT,
                                               float* __restrict__ sT,
                                               int* __restrict__ offs,
                                               int* __restrict__ csrS,
                                               void* __restrict__ out)
{
    __shared__ __align__(16) unsigned char smemRaw[34816];
    __shared__ int csrL[8][64];

    const int tid = threadIdx.x;
    const int p   = (int)blockIdx.x;
    const int G   = (int)gridDim.x;

    // ---- dtype self-probe (all blocks; deterministic) ----
    int pred = 0;
    if (tid < 256) {
        const u32 w = ((const u32*)xin)[tid];
        const int e = (int)((w >> 7) & 0xFFu);
        pred = (e == 0 || (e >= 95 && e <= 140)) ? 1 : 0;
    }
    const int votes = __syncthreads_count(pred);
    const bool bf = votes >= 160;

    if (p == 0) {
        // ---- probes + CSR build ----
        int* cnt = (int*)smemRaw;          // [1000]
        int* cur = cnt + 1000;             // [1000]
        u32 o = 0;
        for (int i = 2 * tid + 1; i < 16000; i += 1024) o |= ew[i];
        const u32 orAll = (u32)__syncthreads_or((int)o);
        const bool i64 = (orAll == 0u);

        for (int i = tid; i < N_; i += 512) cnt[i] = 0;
        __syncthreads();
        for (int e = tid; e < E_; e += 512) {
            const int t = i64 ? (int)ew[2 * (E_ + e)] : (int)ew[E_ + e];
            atomicAdd(&cnt[t], 1);
        }
        __syncthreads();
        // single-wave exclusive scan over 1000 counts: lane l owns 16 idx
        if (tid < 64) {
            int loc[16];
            int s = 0;
#pragma unroll
            for (int i = 0; i < 16; i++) {
                const int idx = tid * 16 + i;
                const int v = (idx < N_) ? cnt[idx] : 0;
                loc[i] = s;
                s += v;
            }
            int run = s;
#pragma unroll
            for (int d = 1; d < 64; d <<= 1) {
                const int up = __shfl_up(run, d, 64);
                if (tid >= d) run += up;
            }
            const int excl = run - s;
#pragma unroll
            for (int i = 0; i < 16; i++) {
                const int idx = tid * 16 + i;
                if (idx < N_) {
                    const int v = excl + loc[i];
                    offs[idx] = v;
                    cur[idx]  = v;
                }
            }
            if (tid == 0) offs[N_] = E_;
        }
        __syncthreads();
        for (int e = tid; e < E_; e += 512) {
            const int s = i64 ? (int)ew[2 * e] : (int)ew[e];
            const int t = i64 ? (int)ew[2 * (E_ + e)] : (int)ew[E_ + e];
            const int pos = atomicAdd(&cur[t], 1);
            csrS[pos] = s * BT;              // pre-scaled for att phase
        }
    } else {
        // ---- GEMM: build W' (permuted) in LDS — vectorized ----
        u16* wl = (u16*)smemRaw;
        if (bf) {
            const short8* wpv = (const short8*)Wp;
            const short8* wsv = (const short8*)Ws;
            for (int i8 = tid; i8 < (HF * FIN) / 8; i8 += 512) {
                const int r = i8 >> 3, c0 = (i8 & 7) * 8;
                *reinterpret_cast<short8*>(wl + wpos(r, c0))       = wpv[i8];
                *reinterpret_cast<short8*>(wl + wpos(128 + r, c0)) = wsv[i8];
            }
        } else {
            const float4* wpv = (const float4*)Wp;
            const float4* wsv = (const float4*)Ws;
            for (int i8 = tid; i8 < (HF * FIN) / 8; i8 += 512) {
                const int r = i8 >> 3, c0 = (i8 & 7) * 8;
                float4 va = wpv[i8 * 2], vb = wpv[i8 * 2 + 1];
                union { short8 v; u16 e[8]; } pk;
                pk.e[0] = f2bf(va.x); pk.e[1] = f2bf(va.y);
                pk.e[2] = f2bf(va.z); pk.e[3] = f2bf(va.w);
                pk.e[4] = f2bf(vb.x); pk.e[5] = f2bf(vb.y);
                pk.e[6] = f2bf(vb.z); pk.e[7] = f2bf(vb.w);
                *reinterpret_cast<short8*>(wl + wpos(r, c0)) = pk.v;
                va = wsv[i8 * 2]; vb = wsv[i8 * 2 + 1];
                pk.e[0] = f2bf(va.x); pk.e[1] = f2bf(va.y);
                pk.e[2] = f2bf(va.z); pk.e[3] = f2bf(va.w);
                pk.e[4] = f2bf(vb.x); pk.e[5] = f2bf(vb.y);
                pk.e[6] = f2bf(vb.z); pk.e[7] = f2bf(vb.w);
                *reinterpret_cast<short8*>(wl + wpos(128 + r, c0)) = pk.v;
            }
        }
        __syncthreads();
        {   // a-fold -> rows 256..263 (aS), 264..271 (aT)
            const int h = tid >> 6, k = tid & 63;
            float s1 = 0.f, s2 = 0.f;
#pragma unroll
            for (int f = 0; f < FOUT; f++) {
                const float w  = bf2f(wl[wpos(h * FOUT + f, k)]);
                const float a1 = bf ? bf2f(((const u16*)as_)[h * FOUT + f])
                                    : ((const float*)as_)[h * FOUT + f];
                const float a2 = bf ? bf2f(((const u16*)at_)[h * FOUT + f])
                                    : ((const float*)at_)[h * FOUT + f];
                s1 = fmaf(a1, w, s1);
                s2 = fmaf(a2, w, s2);
            }
            wl[wpos(256 + h, k)] = f2bf(s1);
            wl[wpos(264 + h, k)] = f2bf(s2);
        }
        __syncthreads();   // W' complete

        const int wid = tid >> 6;
        const int lid = tid & 63;
        const int m   = lid & 15;
        const int q   = lid >> 4;
        const char* WL = (const char*)smemRaw;
        const int   fo = q * 256 + m * 16;

        for (int c = p - 1; c < 750; c += G - 1) {
            const int base = c * 128 + wid * 16;

            short8 x0, x1;
            {
                const size_t xoff = (size_t)(base + m) * FIN + q * 8;
                if (bf) {
                    const u16* xp = (const u16*)xin + xoff;
                    x0 = *reinterpret_cast<const short8*>(xp);
                    x1 = *reinterpret_cast<const short8*>(xp + 32);
                } else {
                    const float* xp = (const float*)xin + xoff;
                    union { short8 v; u16 e[8]; } p0, p1;
#pragma unroll
                    for (int i = 0; i < 8; i++) {
                        p0.e[i] = f2bf(xp[i]);
                        p1.e[i] = f2bf(xp[i + 32]);
                    }
                    x0 = p0.v;
                    x1 = p1.v;
                }
            }

            const u32 rowm = (u32)(base + m);     // row = bt*1000 + n
            const u32 bt   = rowm / 1000u;
            const u32 n    = rowm - bt * 1000u;
            const u32 obm  = n * BT + bt;
            u16* projBase = projT + (size_t)obm * HF;
            u16* skipBase = skipT + (size_t)obm * HF;

#pragma unroll
            for (int t = 0; t < 16; t++) {
                const short8 b0 = *reinterpret_cast<const short8*>(WL + t * 2048 + fo);
                const short8 b1 = *reinterpret_cast<const short8*>(WL + t * 2048 + 1024 + fo);
                float4v acc = {0.f, 0.f, 0.f, 0.f};
                acc = __builtin_amdgcn_mfma_f32_16x16x32_bf16(b0, x0, acc, 0, 0, 0);
                acc = __builtin_amdgcn_mfma_f32_16x16x32_bf16(b1, x1, acc, 0, 0, 0);

                u16* dst = (t < 8) ? projBase : skipBase;
                const int col = ((t < 8) ? t : (t - 8)) * 16 + q * 4;
                uint2 v;
                v.x = pack2bf(acc[0], acc[1]);
                v.y = pack2bf(acc[2], acc[3]);
                *reinterpret_cast<uint2*>(dst + col) = v;
            }
            {   // score tile -> sT cols 0..15 (aS | aT)
                const short8 b0 = *reinterpret_cast<const short8*>(WL + 16 * 2048 + fo);
                const short8 b1 = *reinterpret_cast<const short8*>(WL + 16 * 2048 + 1024 + fo);
                float4v acc = {0.f, 0.f, 0.f, 0.f};
                acc = __builtin_amdgcn_mfma_f32_16x16x32_bf16(b0, x0, acc, 0, 0, 0);
                acc = __builtin_amdgcn_mfma_f32_16x16x32_bf16(b1, x1, acc, 0, 0, 0);
                *reinterpret_cast<float4v*>(sT + (size_t)obm * 16 + q * 4) = acc;
            }
        }
    }

    cg::this_grid().sync();   // device-scope barrier + fence

    // ---- Phase B: attention gather (XCD-pinned, 2 units / block-iter) ----
    const int slot = p & 7;
    const int bis  = (G >> 3) + ((slot < (G & 7)) ? 1 : 0);  // blocks in slot
    const int sidx = p >> 3;
    const int upb  = (1500 + bis - 1) / bis;                 // units per block
    const int j0   = sidx * upb;
    const int j1   = min(1500, j0 + upb);

    const int half = tid >> 8;          // 0/1: which unit of the pair
    const int t256 = tid & 255;
    const int wid4 = t256 >> 6;         // wave within unit: 0..3
    const int wv   = tid >> 6;          // 0..7: csrL row
    const int j2   = tid & 63;
    // weight role
    const int sw  = j2 >> 4;            // edge slot 0..3
    const int bw  = (j2 >> 3) & 1;      // bt half
    const int hw  = j2 & 7;             // head
    // output role
    const int bo  = j2 >> 5;            // bt half
    const int lo5 = j2 & 31;
    const int c0  = lo5 * 4;            // cols c0..c0+3 (single head)
    const int ho  = lo5 >> 2;           // head of those cols

    for (int j = j0; j < j1; j += 2) {
        const int jj = j + half;
        if (jj >= j1) continue;
        const int b  = slot * 1500 + jj;       // virtual unit (R4 remap)
        const int by = b / 1000;               // bt-slice 0..11
        const int n  = b - by * 1000;
        const int btp  = by * 4 + wid4;
        const int bt0  = btp * 2;
        const int bt_w = bt0 + bw;
        const int bt_o = bt0 + bo;

        const float st_w  = sT[((size_t)n * BT + bt_w) * 16 + 8 + hw];
        const int   sboff = bt_w * 16 + hw;        // score addr = csr*16 + sboff
        const u32   oboff = (u32)bt_o * HF + c0;   // proj addr = csr*128 + oboff

        float y0 = 0.f, y1 = 0.f, y2 = 0.f, y3 = 0.f, den = 0.f;
        const int e0 = offs[n], e1 = offs[n + 1];

        for (int base = e0; base < e1; base += 64) {
            const int cnt = min(64, e1 - base);
            csrL[wv][j2] = csrS[base + min(j2, cnt - 1)];   // per-wave tile
            asm volatile("s_waitcnt lgkmcnt(0)" ::: "memory");

            for (int i0 = 0; i0 < cnt; i0 += 4) {
                const int eIdx = i0 + sw;
                const int sBTw = csrL[wv][(eIdx < cnt) ? eIdx : 0];
                const float ss = sT[(size_t)sBTw * 16 + sboff];
                float scv = ss + st_w;
                scv = fmaxf(scv, 0.2f * scv);              // leaky_relu(0.2)
                const float wm = (eIdx < cnt) ? __expf(scv) : 0.f;

#pragma unroll
                for (int k = 0; k < 4; k++) {
                    const float wk = __shfl(wm, k * 16 + bo * 8 + ho, 64);
                    const int sBT = csrL[wv][(i0 + k < cnt) ? (i0 + k) : 0];
                    const uint2 pq = *(const uint2*)(projT + (size_t)sBT * HF + oboff);
                    float f0, f1, f2, f3;
                    unpack2(pq.x, f0, f1);
                    unpack2(pq.y, f2, f3);
                    den += wk;
                    y0 = fmaf(wk, f0, y0);
                    y1 = fmaf(wk, f1, y1);
                    y2 = fmaf(wk, f2, y2);
                    y3 = fmaf(wk, f3, y3);
                }
            }
        }

        const float rden = __builtin_amdgcn_rcpf(den + 1e-16f);
        float sk0, sk1, sk2, sk3;
        {
            const uint2 sq = *(const uint2*)(skipT + ((size_t)n * BT + bt_o) * HF + c0);
            unpack2(sq.x, sk0, sk1);
            unpack2(sq.y, sk2, sk3);
        }
        float o0 = fmaf(y0, rden, sk0);
        float o1 = fmaf(y1, rden, sk1);
        float o2 = fmaf(y2, rden, sk2);
        float o3 = fmaf(y3, rden, sk3);
        o0 = o0 > 0.f ? o0 : __expf(o0) - 1.0f;            // ELU
        o1 = o1 > 0.f ? o1 : __expf(o1) - 1.0f;
        o2 = o2 > 0.f ? o2 : __expf(o2) - 1.0f;
        o3 = o3 > 0.f ? o3 : __expf(o3) - 1.0f;

        const size_t ob = ((size_t)bt_o * N_ + n) * HF + c0;
        if (bf) {
            uint2 v;
            v.x = pack2bf(o0, o1);
            v.y = pack2bf(o2, o3);
            *reinterpret_cast<uint2*>((u16*)out + ob) = v;
        } else {
            *reinterpret_cast<float4*>((float*)out + ob) = make_float4(o0, o1, o2, o3);
        }
    }
}

// ---------------------------------------------------------------------------
extern "C" void kernel_launch(void* const* d_in, const int* in_sizes, int n_in,
                              void* d_out, int out_size, void* d_ws, size_t ws_size,
                              hipStream_t stream)
{
    const void* x   = d_in[0];
    const u32*  ew  = (const u32*)d_in[1];
    const void* Wp  = d_in[2];
    const void* as_ = d_in[3];
    const void* at_ = d_in[4];
    const void* Ws  = d_in[5];

    float* ws    = (float*)d_ws;
    int*   offs  = (int*)(ws + OFF_OFFS);
    int*   csrS  = (int*)(ws + OFF_CSR);
    float* sT    = ws + OFF_ST;
    u16*   projT = (u16*)(ws + OFF_PROJ);
    u16*   skipT = (u16*)(ws + OFF_SKIP);

    static int bpc = 0;
    if (bpc == 0) {
        if (hipOccupancyMaxActiveBlocksPerMultiprocessor(&bpc, k_fused, 512, 0)
                != hipSuccess || bpc < 1)
            bpc = 1;
    }
    int G = bpc * 256;            // MI355X: 256 CUs
    if (G > 751) G = 751;

    void* args[] = { (void*)&x, (void*)&Wp, (void*)&Ws, (void*)&as_, (void*)&at_,
                     (void*)&ew, (void*)&projT, (void*)&skipT, (void*)&sT,
                     (void*)&offs, (void*)&csrS, (void*)&d_out };
    hipLaunchCooperativeKernel(k_fused, dim3(G), dim3(512), args, 0, stream);
}

// Round 7
// 133.744 us; speedup vs baseline: 1.6648x; 1.6648x over previous
//
#include <hip/hip_runtime.h>
#include <math.h>

#define B_   8
#define T_   12
#define BT   96      // B*T
#define N_   1000
#define FIN  64
#define H_   8
#define FOUT 16
#define HF   128     // H*FOUT
#define E_   8000

typedef unsigned short u16;
typedef unsigned int   u32;
typedef __attribute__((ext_vector_type(8))) short  short8;   // 8 bf16 (4 VGPR)
typedef __attribute__((ext_vector_type(4))) float  float4v;  // MFMA acc

__device__ __forceinline__ float bf2f(u16 u) {
    return __uint_as_float(((u32)u) << 16);
}
__device__ __forceinline__ void unpack2(u32 q, float& lo, float& hi) {
    lo = __uint_as_float(q << 16);
    hi = __uint_as_float(q & 0xffff0000u);
}
__device__ __forceinline__ u16 f2bf(float f) {
    u32 x = __float_as_uint(f);
    u32 r = (x + 0x7fffu + ((x >> 16) & 1u)) >> 16;   // RNE
    return (u16)r;
}
__device__ __forceinline__ u32 pack2bf(float lo, float hi) {
    return (u32)f2bf(lo) | ((u32)f2bf(hi) << 16);
}

// Fragment-permuted W' layout (see R2): conflict-free ds_read_b128 fragments.
__device__ __forceinline__ int wpos(int r, int c) {
    return (((r >> 4) * 8 + (c >> 5) * 4 + ((c >> 3) & 3)) * 16 + (r & 15)) * 8
           + (c & 7);
}

// ---------------------------------------------------------------------------
// Workspace carve (float-element offsets).
// ROW-MAJOR intermediates (R7): projT/skipT bf16 [bt*1000+n][128],
// sT fp32 [bt*1000+n][16]. GEMM stores become 16-segment (was 64-segment)
// per store instruction; k_att bt-slice working set becomes one contiguous
// 2 MB block per 8-bt slice (cleaner XCD-L2 pinning).
// ---------------------------------------------------------------------------
#define OFF_FLAGS   0         // 4 ints
#define OFF_OFFS    264       // 1004 ints
#define OFF_CSR     1268      // 8000 ints (raw src, grouped by target)
#define OFF_ST      17972     // 1536000 sT fp32 [row][16]
#define OFF_PROJ    1553972   // projT bf16 [row][128] = 12.288M u16
#define OFF_SKIP    7697972   // skipT bf16 [row][128]

// ---------------------------------------------------------------------------
// K1: MFMA GEMM  C[96000 x 272] = X[96000 x 64] . W'^T, row-major outputs.
// Each GEMM block self-probes the x dtype and builds W' (proj | skip |
// aS-fold | aT-fold) in LDS from the raw L2-hot weights (vectorized).
// Block 0 = probes + CSR build (single-wave shfl scan); GEMM = blocks 1..750.
// ---------------------------------------------------------------------------
__global__ __launch_bounds__(512) void k_mfma(const void* __restrict__ xin,
                                              const void* __restrict__ Wp,
                                              const void* __restrict__ Ws,
                                              const void* __restrict__ as_,
                                              const void* __restrict__ at_,
                                              const u32* __restrict__ ew,
                                              int* __restrict__ flags,
                                              u16* __restrict__ projT,
                                              u16* __restrict__ skipT,
                                              float* __restrict__ sT,
                                              int* __restrict__ offs,
                                              int* __restrict__ csrS)
{
    __shared__ __align__(16) unsigned char smemRaw[34816];

    const int tid = threadIdx.x;

    if (blockIdx.x == 0) {
        // ---- probes + CSR build (1 block, overlapped with GEMM blocks) ----
        int* cnt = (int*)smemRaw;          // [1000]
        int* cur = cnt + 1000;             // [1000]

        int pred = 0;
        if (tid < 256) {   // bf16-vs-fp32 probe on x
            const u32 w = ((const u32*)xin)[tid];
            const int e = (int)((w >> 7) & 0xFFu);
            pred = (e == 0 || (e >= 95 && e <= 140)) ? 1 : 0;
        }
        const int votes = __syncthreads_count(pred);
        u32 o = 0;
        for (int i = 2 * tid + 1; i < 16000; i += 1024) o |= ew[i];
        const u32 orAll = (u32)__syncthreads_or((int)o);
        const bool i64 = (orAll == 0u);
        if (tid == 0) {
            flags[0] = (votes >= 160) ? 1 : 0;
            flags[1] = i64 ? 1 : 0;
        }

        for (int i = tid; i < N_; i += 512) cnt[i] = 0;
        __syncthreads();
        for (int e = tid; e < E_; e += 512) {
            const int t = i64 ? (int)ew[2 * (E_ + e)] : (int)ew[E_ + e];
            atomicAdd(&cnt[t], 1);
        }
        __syncthreads();
        // single-wave exclusive scan over 1000 counts: lane l owns 16 idx
        if (tid < 64) {
            int loc[16];
            int s = 0;
#pragma unroll
            for (int i = 0; i < 16; i++) {
                const int idx = tid * 16 + i;
                const int v = (idx < N_) ? cnt[idx] : 0;
                loc[i] = s;              // lane-local exclusive prefix
                s += v;
            }
            int run = s;                 // wave inclusive scan of lane sums
#pragma unroll
            for (int d = 1; d < 64; d <<= 1) {
                const int up = __shfl_up(run, d, 64);
                if (tid >= d) run += up;
            }
            const int excl = run - s;    // wave exclusive prefix
#pragma unroll
            for (int i = 0; i < 16; i++) {
                const int idx = tid * 16 + i;
                if (idx < N_) {
                    const int v = excl + loc[i];
                    offs[idx] = v;
                    cur[idx]  = v;
                }
            }
            if (tid == 0) offs[N_] = E_;
        }
        __syncthreads();
        for (int e = tid; e < E_; e += 512) {
            const int s = i64 ? (int)ew[2 * e] : (int)ew[e];
            const int t = i64 ? (int)ew[2 * (E_ + e)] : (int)ew[E_ + e];
            const int pos = atomicAdd(&cur[t], 1);
            csrS[pos] = s;                   // raw src (shifted in k_att)
        }
        return;
    }

    // ---- GEMM path (blocks 1..750) ----
    // self-probe x dtype (identical criterion to block 0; deterministic)
    int pred = 0;
    if (tid < 256) {
        const u32 w = ((const u32*)xin)[tid];
        const int e = (int)((w >> 7) & 0xFFu);
        pred = (e == 0 || (e >= 95 && e <= 140)) ? 1 : 0;
    }
    const int votes = __syncthreads_count(pred);
    const bool bf = votes >= 160;

    const int wid  = tid >> 6;
    const int lid  = tid & 63;
    const int m    = lid & 15;
    const int q    = lid >> 4;
    const int base = (blockIdx.x - 1) * 128 + wid * 16;

    // issue X load early; W' build below hides its latency
    short8 x0, x1;   // X fragment (B-operand)
    {
        const size_t xoff = (size_t)(base + m) * FIN + q * 8;
        if (bf) {
            const u16* xp = (const u16*)xin + xoff;
            x0 = *reinterpret_cast<const short8*>(xp);
            x1 = *reinterpret_cast<const short8*>(xp + 32);
        } else {
            const float* xp = (const float*)xin + xoff;
            union { short8 v; u16 e[8]; } p0, p1;
#pragma unroll
            for (int i = 0; i < 8; i++) {
                p0.e[i] = f2bf(xp[i]);
                p1.e[i] = f2bf(xp[i + 32]);
            }
            x0 = p0.v;
            x1 = p1.v;
        }
    }

    // build W' (permuted) in LDS — vectorized: 8 cols per iter
    u16* wl = (u16*)smemRaw;
    if (bf) {
        const short8* wpv = (const short8*)Wp;
        const short8* wsv = (const short8*)Ws;
        for (int i8 = tid; i8 < (HF * FIN) / 8; i8 += 512) {
            const int r = i8 >> 3, c0 = (i8 & 7) * 8;
            *reinterpret_cast<short8*>(wl + wpos(r, c0))       = wpv[i8];
            *reinterpret_cast<short8*>(wl + wpos(128 + r, c0)) = wsv[i8];
        }
    } else {
        const float4* wpv = (const float4*)Wp;
        const float4* wsv = (const float4*)Ws;
        for (int i8 = tid; i8 < (HF * FIN) / 8; i8 += 512) {
            const int r = i8 >> 3, c0 = (i8 & 7) * 8;
            float4 va = wpv[i8 * 2], vb = wpv[i8 * 2 + 1];
            union { short8 v; u16 e[8]; } p;
            p.e[0] = f2bf(va.x); p.e[1] = f2bf(va.y);
            p.e[2] = f2bf(va.z); p.e[3] = f2bf(va.w);
            p.e[4] = f2bf(vb.x); p.e[5] = f2bf(vb.y);
            p.e[6] = f2bf(vb.z); p.e[7] = f2bf(vb.w);
            *reinterpret_cast<short8*>(wl + wpos(r, c0)) = p.v;
            va = wsv[i8 * 2]; vb = wsv[i8 * 2 + 1];
            p.e[0] = f2bf(va.x); p.e[1] = f2bf(va.y);
            p.e[2] = f2bf(va.z); p.e[3] = f2bf(va.w);
            p.e[4] = f2bf(vb.x); p.e[5] = f2bf(vb.y);
            p.e[6] = f2bf(vb.z); p.e[7] = f2bf(vb.w);
            *reinterpret_cast<short8*>(wl + wpos(128 + r, c0)) = p.v;
        }
    }
    __syncthreads();
    {   // a-fold: thread -> (h, k); writes tile-16 region (disjoint from reads)
        const int h = tid >> 6, k = tid & 63;
        float s1 = 0.f, s2 = 0.f;
#pragma unroll
        for (int f = 0; f < FOUT; f++) {
            const float w  = bf2f(wl[wpos(h * FOUT + f, k)]);
            const float a1 = bf ? bf2f(((const u16*)as_)[h * FOUT + f])
                                : ((const float*)as_)[h * FOUT + f];
            const float a2 = bf ? bf2f(((const u16*)at_)[h * FOUT + f])
                                : ((const float*)at_)[h * FOUT + f];
            s1 = fmaf(a1, w, s1);
            s2 = fmaf(a2, w, s2);
        }
        wl[wpos(256 + h, k)] = f2bf(s1);   // aS rows
        wl[wpos(264 + h, k)] = f2bf(s2);   // aT rows
    }

    // ROW-MAJOR outputs: row = bt*1000 + n directly (no div/mod)
    const u32 row = (u32)(base + m);
    u16* projBase = projT + (size_t)row * HF;
    u16* skipBase = skipT + (size_t)row * HF;

    __syncthreads();   // W' complete

    const char* WL = (const char*)smemRaw;
    const int   fo = q * 256 + m * 16;   // per-lane fragment byte offset

#pragma unroll
    for (int t = 0; t < 16; t++) {
        const short8 b0 = *reinterpret_cast<const short8*>(WL + t * 2048 + fo);
        const short8 b1 = *reinterpret_cast<const short8*>(WL + t * 2048 + 1024 + fo);
        float4v acc = {0.f, 0.f, 0.f, 0.f};
        acc = __builtin_amdgcn_mfma_f32_16x16x32_bf16(b0, x0, acc, 0, 0, 0);
        acc = __builtin_amdgcn_mfma_f32_16x16x32_bf16(b1, x1, acc, 0, 0, 0);

        u16* dst = (t < 8) ? projBase : skipBase;
        const int col = ((t < 8) ? t : (t - 8)) * 16 + q * 4;
        uint2 v;
        v.x = pack2bf(acc[0], acc[1]);
        v.y = pack2bf(acc[2], acc[3]);
        *reinterpret_cast<uint2*>(dst + col) = v;   // 8B store, 32B/4-lane seg
    }

    {   // score tile: W' rows 256..271 -> sT cols 0..15 (aS | aT)
        const short8 b0 = *reinterpret_cast<const short8*>(WL + 16 * 2048 + fo);
        const short8 b1 = *reinterpret_cast<const short8*>(WL + 16 * 2048 + 1024 + fo);
        float4v acc = {0.f, 0.f, 0.f, 0.f};
        acc = __builtin_amdgcn_mfma_f32_16x16x32_bf16(b0, x0, acc, 0, 0, 0);
        acc = __builtin_amdgcn_mfma_f32_16x16x32_bf16(b1, x1, acc, 0, 0, 0);
        *reinterpret_cast<float4v*>(sT + (size_t)row * 16 + q * 4) = acc; // 64B/4-lane
    }
}

// ---------------------------------------------------------------------------
// K2: attention gather, 2 bt per wave, XCD-pinned bt-slices. grid 12000.
// Block decode: b = (wg&7)*1500 + (wg>>3); by = b/1000; n = b%1000 —
// each bt-slice's working set (contiguous 2 MB proj + 0.5 MB sT) pins to
// <=2 XCD L2s (R4: -12 us). R4's proven loop structure (LDS csrL, block
// barriers); addressing updated for row-major intermediates: addr bases
// are bt*<stride> and the gathered src contributes (src<<7)/(src<<4).
// No global-max subtraction: softmax is shift-invariant and scores are
// structurally bounded (|s| <~ 15 << 88), so exp cannot overflow.
// ---------------------------------------------------------------------------
__global__ __launch_bounds__(256) void k_att(const u16* __restrict__ projT,
                                             const u16* __restrict__ skipT,
                                             const float* __restrict__ sT,
                                             const int* __restrict__ offs,
                                             const int* __restrict__ csrS,
                                             const int* __restrict__ flags,
                                             void* __restrict__ out)
{
    const int wg  = blockIdx.x;                    // 0..11999
    const int b   = (wg & 7) * 1500 + (wg >> 3);   // XCD-pinned remap
    const int by  = b / 1000;                      // bt-slice 0..11
    const int n   = b - by * 1000;
    const int tid = threadIdx.x;
    const int btp = by * 4 + (tid >> 6);           // 0..47
    const int bt0 = btp * 2;
    const int j2  = tid & 63;
    // weight role
    const int sw  = j2 >> 4;          // edge slot 0..3
    const int bw  = (j2 >> 3) & 1;    // bt half
    const int hw  = j2 & 7;           // head
    // output role
    const int bo  = j2 >> 5;          // bt half
    const int lo5 = j2 & 31;
    const int c0  = lo5 * 4;          // cols c0..c0+3 (single head)
    const int ho  = lo5 >> 2;         // head of those cols

    __shared__ int csrL[64];          // raw src

    const int bt_w = bt0 + bw;
    const int bt_o = bt0 + bo;
    const float st_w   = sT[((size_t)bt_w * N_ + n) * 16 + 8 + hw];
    const int   stoff  = bt_w * (N_ * 16) + hw;   // score = stoff + (src<<4)
    const u32   proff  = (u32)bt_o * (N_ * HF) + c0; // proj = proff + (src<<7)

    float y0 = 0.f, y1 = 0.f, y2 = 0.f, y3 = 0.f, den = 0.f;
    const int e0 = offs[n], e1 = offs[n + 1];

    for (int base = e0; base < e1; base += 64) {
        const int cnt = min(64, e1 - base);
        __syncthreads();
        if (tid < cnt) csrL[tid] = csrS[base + tid];
        __syncthreads();

        for (int i0 = 0; i0 < cnt; i0 += 4) {
            // weight role: one exp per lane (4 edges x 2 bt x 8 heads)
            const int eIdx = i0 + sw;
            const int sW   = csrL[(eIdx < cnt) ? eIdx : 0];
            const float ss = sT[(size_t)(stoff + (sW << 4))];
            float scv = ss + st_w;
            scv = fmaxf(scv, 0.2f * scv);               // leaky_relu(0.2)
            const float wm = (eIdx < cnt) ? __expf(scv) : 0.f;

            // accumulate 4 edges; weight for (edge k, bt bo, head ho)
#pragma unroll
            for (int k = 0; k < 4; k++) {
                const float wk = __shfl(wm, k * 16 + bo * 8 + ho, 64);
                const int sv = csrL[(i0 + k < cnt) ? (i0 + k) : 0];
                const uint2 pq = *(const uint2*)(projT + proff + ((size_t)sv << 7));
                float f0, f1, f2, f3;
                unpack2(pq.x, f0, f1);
                unpack2(pq.y, f2, f3);
                den += wk;
                y0 = fmaf(wk, f0, y0);
                y1 = fmaf(wk, f1, y1);
                y2 = fmaf(wk, f2, y2);
                y3 = fmaf(wk, f3, y3);
            }
        }
    }

    const float rden = __builtin_amdgcn_rcpf(den + 1e-16f);
    float sk0, sk1, sk2, sk3;
    {
        const uint2 sq = *(const uint2*)(skipT + ((size_t)bt_o * N_ + n) * HF + c0);
        unpack2(sq.x, sk0, sk1);
        unpack2(sq.y, sk2, sk3);
    }
    float o0 = fmaf(y0, rden, sk0);
    float o1 = fmaf(y1, rden, sk1);
    float o2 = fmaf(y2, rden, sk2);
    float o3 = fmaf(y3, rden, sk3);
    o0 = o0 > 0.f ? o0 : __expf(o0) - 1.0f;             // ELU (bf16-exact enough)
    o1 = o1 > 0.f ? o1 : __expf(o1) - 1.0f;
    o2 = o2 > 0.f ? o2 : __expf(o2) - 1.0f;
    o3 = o3 > 0.f ? o3 : __expf(o3) - 1.0f;

    const size_t ob = ((size_t)bt_o * N_ + n) * HF + c0;
    if (flags[0]) {
        uint2 v;
        v.x = pack2bf(o0, o1);
        v.y = pack2bf(o2, o3);
        *reinterpret_cast<uint2*>((u16*)out + ob) = v;
    } else {
        *reinterpret_cast<float4*>((float*)out + ob) = make_float4(o0, o1, o2, o3);
    }
}

// ---------------------------------------------------------------------------
extern "C" void kernel_launch(void* const* d_in, const int* in_sizes, int n_in,
                              void* d_out, int out_size, void* d_ws, size_t ws_size,
                              hipStream_t stream)
{
    const void* x   = d_in[0];
    const u32*  ew  = (const u32*)d_in[1];
    const void* Wp  = d_in[2];
    const void* as_ = d_in[3];
    const void* at_ = d_in[4];
    const void* Ws  = d_in[5];

    float* ws    = (float*)d_ws;
    int*   flags = (int*)(ws + OFF_FLAGS);
    int*   offs  = (int*)(ws + OFF_OFFS);
    int*   csrS  = (int*)(ws + OFF_CSR);
    float* sT    = ws + OFF_ST;
    u16*   projT = (u16*)(ws + OFF_PROJ);
    u16*   skipT = (u16*)(ws + OFF_SKIP);

    k_mfma<<<751, 512, 0, stream>>>(x, Wp, Ws, as_, at_, ew, flags,
                                    projT, skipT, sT, offs, csrS);
    k_att <<<12000, 256, 0, stream>>>(projT, skipT, sT,
                                      offs, csrS, flags, d_out);
}